// Round 3
// baseline (569.687 us; speedup 1.0000x reference)
//
#include <hip/hip_runtime.h>

// Problem constants (fixed by the reference).
constexpr int Bn = 4;       // batch
constexpr int Tn = 2048;    // seq len
constexpr int Dn = 1024;    // hidden
constexpr int Rn = 64;      // max relative position
constexpr int RELP = 256;   // rel rows padded to 256
constexpr int QR_STRIDE = 132;

typedef __bf16 bf8 __attribute__((ext_vector_type(8)));
typedef float f32x4 __attribute__((ext_vector_type(4)));

__device__ __forceinline__ unsigned short f2bf(float f) {
    unsigned int u = __float_as_uint(f);
    u += 0x7fffu + ((u >> 16) & 1u);     // round-to-nearest-even
    return (unsigned short)(u >> 16);
}

#define GLDS(g, l)                                                            \
    __builtin_amdgcn_global_load_lds(                                         \
        (const __attribute__((address_space(1))) void*)(g),                   \
        (__attribute__((address_space(3))) void*)(l), 16, 0, 0)

#define MFMA_BF16(a, b, c) __builtin_amdgcn_mfma_f32_16x16x32_bf16(a, b, c, 0, 0, 0)

// sched_barrier(0) pins phase boundaries; s_barrier is RAW (no vmcnt drain).
#define SBAR()                                                                \
    do {                                                                      \
        __builtin_amdgcn_sched_barrier(0);                                    \
        __builtin_amdgcn_s_barrier();                                         \
    } while (0)

// ===========================================================================
// 256x256 GEMM, BK=32, 8 waves (2M x 4N), K=1024 -> 32 K-tiles.
// LDS: A,B each a 3-deep ring of [256][32] bf16 K-tile slots (16 KB/slot,
// 96 KB total -> 1 block/CU, 2 waves/SIMD).
// T2 swizzle (both-sides): K-tile stored as 128 physical rows of 128 B
// (8 x 16B chunks). Logical chunk c = row*4 + col8 (row 0..255, col8 0..3)
// lives at physical (prow = c>>3, pchunk = (c&7) ^ (prow&7)).
// GLDS writes LINEARLY (thread tid, load j -> physical chunk j*512+tid);
// the global SOURCE address is inverse-permuted so the right data lands
// there. ds_read applies the same XOR. 64 lanes of a b128 read then spread
// uniformly: each 16B slot hit by exactly 8 lanes (optimal, m201-grade).
// Pipeline (T3+T4): tile t in slot t%3. Iter T: 2 phases, each
// {ds_read frags | stage 2 GLDS of tile T+2 | SBAR | setprio+16 MFMA | SBAR};
// counted vmcnt(4) once per tile (tile T+2's 4 loads stay in flight,
// tile T+1 resident), vmcnt(0) only at tile NT-2. T5 setprio in phases.
// ===========================================================================
__device__ __forceinline__ void mfma_gemm_256_k32(
    const unsigned short* __restrict__ Ab,   // [256 rows][K=1024], tile base
    const unsigned short* __restrict__ Bb,   // [256 rows][K=1024], tile base
    f32x4 (&acc)[8][4], unsigned short* As, unsigned short* Bs)
{
    const int tid  = threadIdx.x;
    const int lane = tid & 63, wid = tid >> 6;
    const int wr = wid >> 2, wc = wid & 3;
    const int l15 = lane & 15, lq = lane >> 4;

    // swizzled per-lane ds_read offset (ushorts), shared by every fragment:
    // frag row r = base16 + l15 (base16 multiple of 16), so
    // pc = ((l15&1)*4+lq) ^ ((l15>>1)&7), off = (l15>>1)*64 + pc*8.
    const int pc = (((l15 & 1) << 2) | lq) ^ ((l15 >> 1) & 7);
    const int lane_off = ((l15 >> 1) << 6) + (pc << 3);
    const int aoff = wr * 4096 + lane_off;   // + mi*512 (mi 0..7)
    const int boff = wc * 2048 + lane_off;   // + ni*512 (ni 0..3)

    // staging: thread tid handles physical chunks P0=tid, P1=tid+512.
    // invert swizzle: crow = P>>3, c = crow*8 + ((P&7)^(crow&7)),
    // global src elem = (c>>2)*Dn + (c&3)*8.
    const int P0 = tid, P1 = tid + 512;
    const int cr0 = P0 >> 3, cr1 = P1 >> 3;
    const int c0 = cr0 * 8 + ((P0 & 7) ^ (cr0 & 7));
    const int c1 = cr1 * 8 + ((P1 & 7) ^ (cr1 & 7));
    const size_t g0 = (size_t)(c0 >> 2) * Dn + (size_t)((c0 & 3) << 3);
    const size_t g1 = (size_t)(c1 >> 2) * Dn + (size_t)((c1 & 3) << 3);
    const int d0 = P0 * 8, d1 = P1 * 8;      // ushort offsets within slot

#define STAGE(src, buf)                                                       \
    do {                                                                      \
        GLDS((src) + g0, (buf) + d0);                                         \
        GLDS((src) + g1, (buf) + d1);                                         \
    } while (0)

    constexpr int NT = Dn / 32;              // 32 K-tiles

    // prologue: tile 0 -> slot 0, tile 1 -> slot 1 (issue order: A0,B0,A1,B1)
    STAGE(Ab, As);
    STAGE(Bb, Bs);
    STAGE(Ab + 32, As + 8192);
    STAGE(Bb + 32, Bs + 8192);
    asm volatile("s_waitcnt vmcnt(4)" ::: "memory");   // tile 0 resident
    SBAR();

    int bufi = 0;
    bf8 a8[8], b4[4];
#pragma unroll 1
    for (int T = 0; T < NT; ++T) {
        const int cb  = bufi << 13;                        // compute slot
        const int sb  = (bufi == 0 ? 2 : bufi - 1) << 13;  // (bufi+2)%3 slot
        const bool st = T < NT - 2;
        const unsigned short* At = Ab + (T + 2) * 32;
        const unsigned short* Bt = Bb + (T + 2) * 32;

        // ---- phase 0: read A mi0-7 + B ni0-1; stage A(T+2); MFMA ni0-1
#pragma unroll
        for (int m = 0; m < 8; ++m)
            a8[m] = *(const bf8*)&As[cb + aoff + m * 512];
        b4[0] = *(const bf8*)&Bs[cb + boff];
        b4[1] = *(const bf8*)&Bs[cb + boff + 512];
        if (st) STAGE(At, As + sb);
        SBAR();
        __builtin_amdgcn_s_setprio(1);
#pragma unroll
        for (int m = 0; m < 8; ++m) {
            acc[m][0] = MFMA_BF16(a8[m], b4[0], acc[m][0]);
            acc[m][1] = MFMA_BF16(a8[m], b4[1], acc[m][1]);
        }
        __builtin_amdgcn_s_setprio(0);
        SBAR();

        // ---- phase 1: read B ni2-3; stage B(T+2); MFMA ni2-3
        b4[2] = *(const bf8*)&Bs[cb + boff + 1024];
        b4[3] = *(const bf8*)&Bs[cb + boff + 1536];
        if (st) STAGE(Bt, Bs + sb);
        SBAR();
        __builtin_amdgcn_s_setprio(1);
#pragma unroll
        for (int m = 0; m < 8; ++m) {
            acc[m][2] = MFMA_BF16(a8[m], b4[2], acc[m][2]);
            acc[m][3] = MFMA_BF16(a8[m], b4[3], acc[m][3]);
        }
        __builtin_amdgcn_s_setprio(0);
        if (st) {
            // retire tile T+1's 4 loads; tile T+2's 4 stay in flight
            asm volatile("s_waitcnt vmcnt(4)" ::: "memory");
        } else if (T == NT - 2) {
            asm volatile("s_waitcnt vmcnt(0)" ::: "memory");  // tail drain
        }
        if (T < NT - 1) SBAR();
        bufi = (bufi == 2) ? 0 : bufi + 1;
    }
#undef STAGE
}

// ---------------------------------------------------------------------------
// 128x128 legacy mainloop (kept for qr_gemm — tiny op, known-good)
// ---------------------------------------------------------------------------
__device__ __forceinline__ void mfma_gemm_128(
    const unsigned short* __restrict__ Ab,
    const unsigned short* __restrict__ Bb,
    int K, f32x4 acc[4][4],
    unsigned short* As, unsigned short* Bs)  // [2*128*32] each
{
    const int tid = threadIdx.x;
    const int r0  = tid >> 2;
    const int c8  = (tid & 3) * 8;
    const int lane = tid & 63;
    const int w    = tid >> 6;
    const int wm = (w & 1) * 64, wn = (w >> 1) * 64;
    const int l15 = lane & 15, lq = lane >> 4;

    const int nt = K >> 5;

    GLDS(Ab + (size_t)r0 * K + c8,        As + r0 * 32 + c8);
    GLDS(Ab + ((size_t)r0 + 64) * K + c8, As + (r0 + 64) * 32 + c8);
    GLDS(Bb + (size_t)r0 * K + c8,        Bs + r0 * 32 + c8);
    GLDS(Bb + ((size_t)r0 + 64) * K + c8, Bs + (r0 + 64) * 32 + c8);
    __syncthreads();

    int cur = 0;
    for (int t = 0; t < nt; ++t) {
        if (t + 1 < nt) {
            const int k0 = (t + 1) << 5;
            const int nb = (cur ^ 1) * (128 * 32);
            GLDS(Ab + (size_t)r0 * K + k0 + c8,        As + nb + r0 * 32 + c8);
            GLDS(Ab + ((size_t)r0 + 64) * K + k0 + c8, As + nb + (r0 + 64) * 32 + c8);
            GLDS(Bb + (size_t)r0 * K + k0 + c8,        Bs + nb + r0 * 32 + c8);
            GLDS(Bb + ((size_t)r0 + 64) * K + k0 + c8, Bs + nb + (r0 + 64) * 32 + c8);
        }
        const int cbuf = cur * (128 * 32);
        bf8 a[4], b[4];
#pragma unroll
        for (int i = 0; i < 4; ++i) {
            a[i] = *(const bf8*)&As[cbuf + (wm + i * 16 + l15) * 32 + lq * 8];
            b[i] = *(const bf8*)&Bs[cbuf + (wn + i * 16 + l15) * 32 + lq * 8];
        }
#pragma unroll
        for (int i = 0; i < 4; ++i)
#pragma unroll
            for (int j = 0; j < 4; ++j)
                acc[i][j] = MFMA_BF16(a[i], b[j], acc[i][j]);
        __syncthreads();
        cur ^= 1;
    }
}

// ---------------------------------------------------------------------------
// Prep kernels
// ---------------------------------------------------------------------------
__global__ __launch_bounds__(256) void cvt_bf16(
    const float* __restrict__ in, unsigned short* __restrict__ out, int n4)
{
    int i = blockIdx.x * 256 + threadIdx.x;
    if (i < n4) {
        float4 v = ((const float4*)in)[i];
        ushort4 o;
        o.x = f2bf(v.x); o.y = f2bf(v.y); o.z = f2bf(v.z); o.w = f2bf(v.w);
        ((ushort4*)out)[i] = o;
    }
}

__global__ __launch_bounds__(256) void wt_transpose(
    const float* __restrict__ w0, const float* __restrict__ w1,
    const float* __restrict__ w2, const float* __restrict__ w3,
    unsigned short* __restrict__ WT)
{
    __shared__ float t[32][33];
    const int z = blockIdx.z;
    const float* W = z == 0 ? w0 : z == 1 ? w1 : z == 2 ? w2 : w3;
    const int x = blockIdx.x * 32 + threadIdx.x;   // n
    const int y0 = blockIdx.y * 32;                // k
#pragma unroll
    for (int j = 0; j < 32; j += 8)
        t[threadIdx.y + j][threadIdx.x] = W[(size_t)(y0 + threadIdx.y + j) * Dn + x];
    __syncthreads();
    unsigned short* o = WT + (size_t)z * Dn * Dn;
    const int n0 = blockIdx.x * 32;
#pragma unroll
    for (int j = 0; j < 32; j += 8)
        o[(size_t)(n0 + threadIdx.y + j) * Dn + y0 + threadIdx.x] =
            f2bf(t[threadIdx.x][threadIdx.y + j]);
}

__global__ __launch_bounds__(256) void rel_pad(
    const float* __restrict__ st_rel, const float* __restrict__ ed_rel,
    unsigned short* __restrict__ relb)
{
    const int z = blockIdx.y;
    const float* in = z ? ed_rel : st_rel;
    const int i4 = blockIdx.x * 256 + threadIdx.x;
    const int row = (i4 * 4) >> 10;
    const int col = (i4 * 4) & 1023;
    ushort4 o; o.x = 0; o.y = 0; o.z = 0; o.w = 0;
    if (row < 2 * Rn + 1) {
        float4 v = *(const float4*)(in + (size_t)row * 1024 + col);
        o.x = f2bf(v.x); o.y = f2bf(v.y); o.z = f2bf(v.z); o.w = f2bf(v.w);
    }
    ((ushort4*)(relb + (size_t)z * RELP * 1024))[i4] = o;
}

// ---------------------------------------------------------------------------
// Projections (256², BK=32 ring-3): out[z] = bf16((X @ W[z]^T + b[z]) * scale)
// ---------------------------------------------------------------------------
__global__ __launch_bounds__(512, 2) void proj_gemm256(
    const unsigned short* __restrict__ Xb, const unsigned short* __restrict__ Wb,
    const float* __restrict__ b0, const float* __restrict__ b1,
    const float* __restrict__ b2, const float* __restrict__ b3,
    unsigned short* __restrict__ outQK, float qscale)
{
    __shared__ unsigned short As[3 * 8192], Bs[3 * 8192];   // 96 KB total
    const int z = blockIdx.z;
    const float* bias = z == 0 ? b0 : z == 1 ? b1 : z == 2 ? b2 : b3;
    const float scale = (z & 1) ? 1.0f : qscale;

    const unsigned short* Ab = Xb + (size_t)blockIdx.x * 256 * Dn;
    const unsigned short* Bb = Wb + ((size_t)z * Dn + blockIdx.y * 256) * Dn;

    f32x4 zero = {0.f, 0.f, 0.f, 0.f};
    f32x4 acc[8][4];
#pragma unroll
    for (int i = 0; i < 8; ++i)
#pragma unroll
        for (int j = 0; j < 4; ++j) acc[i][j] = zero;

    mfma_gemm_256_k32(Ab, Bb, acc, As, Bs);

    const int tid = threadIdx.x, lane = tid & 63, wid = tid >> 6;
    const int wr = wid >> 2, wc = wid & 3;
    const int l15 = lane & 15, lq = lane >> 4;
    unsigned short* out = outQK + (size_t)z * (size_t)Bn * Tn * Dn;
    const int row0 = blockIdx.x * 256 + wr * 128 + lq * 4;
    const int col0 = blockIdx.y * 256 + wc * 64 + l15;

#pragma unroll
    for (int ni = 0; ni < 4; ++ni) {
        const int col = col0 + ni * 16;
        const float bvv = bias[col];
#pragma unroll
        for (int mi = 0; mi < 8; ++mi)
#pragma unroll
            for (int r = 0; r < 4; ++r) {
                const int row = row0 + mi * 16 + r;
                out[(size_t)row * Dn + col] = f2bf((acc[mi][ni][r] + bvv) * scale);
            }
    }
}

// ---------------------------------------------------------------------------
// qr[z] = Q[z] @ rel[z]^T (legacy 128² path — tiny op)
// ---------------------------------------------------------------------------
__global__ __launch_bounds__(256) void qr_gemm(
    const unsigned short* __restrict__ QKb, const unsigned short* __restrict__ relb,
    float* __restrict__ QR)
{
    __shared__ unsigned short As[2 * 128 * 32], Bs[2 * 128 * 32];
    const int z = blockIdx.z;
    const unsigned short* Ab = QKb + ((size_t)(z * 2) * Bn * Tn + blockIdx.x * 128) * Dn;
    const unsigned short* Bb = relb + ((size_t)z * RELP + blockIdx.y * 128) * Dn;

    f32x4 zero = {0.f, 0.f, 0.f, 0.f};
    f32x4 acc[4][4];
#pragma unroll
    for (int i = 0; i < 4; ++i)
#pragma unroll
        for (int j = 0; j < 4; ++j) acc[i][j] = zero;

    mfma_gemm_128(Ab, Bb, Dn, acc, As, Bs);

    const int tid = threadIdx.x, lane = tid & 63, w = tid >> 6;
    const int wm = (w & 1) * 64, wn = (w >> 1) * 64;
    const int l15 = lane & 15, lq = lane >> 4;
    float* out = QR + (size_t)z * (size_t)Bn * Tn * QR_STRIDE;

#pragma unroll
    for (int ni = 0; ni < 4; ++ni) {
        const int col = blockIdx.y * 128 + wn + ni * 16 + l15;
        if (col >= 2 * Rn + 1) continue;
#pragma unroll
        for (int mi = 0; mi < 4; ++mi) {
#pragma unroll
            for (int r = 0; r < 4; ++r) {
                const int row = blockIdx.x * 128 + wm + mi * 16 + lq * 4 + r;
                out[(size_t)row * QR_STRIDE + col] = acc[mi][ni][r];
            }
        }
    }
}

// ---------------------------------------------------------------------------
// scores (256², BK=32 ring-3):
// Out[side,bt,i,j] = mask ? Q·K^T + qr[i,clip(j-i)] : -1e18
// ---------------------------------------------------------------------------
__global__ __launch_bounds__(512, 2) void scores_gemm256(
    const unsigned short* __restrict__ QKb, const float* __restrict__ QR,
    const int* __restrict__ mask, float* __restrict__ Out)
{
    __shared__ unsigned short As[3 * 8192], Bs[3 * 8192];   // 96 KB total
    const int z = blockIdx.z;
    const int side = z >> 2, bt = z & 3;

    const unsigned short* Ab =
        QKb + ((size_t)side * 2 * Bn * Tn + (size_t)bt * Tn + blockIdx.x * 256) * Dn;
    const unsigned short* Bb =
        QKb + (((size_t)side * 2 + 1) * Bn * Tn + (size_t)bt * Tn + blockIdx.y * 256) * Dn;
    const float* QRb = QR + ((size_t)side * Bn * Tn + (size_t)bt * Tn) * QR_STRIDE;
    const int* maskb = mask + (size_t)bt * Tn * Tn;
    float* outb = Out + ((size_t)side * Bn + bt) * (size_t)Tn * Tn;

    f32x4 zero = {0.f, 0.f, 0.f, 0.f};
    f32x4 acc[8][4];
#pragma unroll
    for (int i = 0; i < 8; ++i)
#pragma unroll
        for (int j = 0; j < 4; ++j) acc[i][j] = zero;

    mfma_gemm_256_k32(Ab, Bb, acc, As, Bs);

    const int tid = threadIdx.x, lane = tid & 63, wid = tid >> 6;
    const int wr = wid >> 2, wc = wid & 3;
    const int l15 = lane & 15, lq = lane >> 4;
    const int i0 = blockIdx.x * 256 + wr * 128 + lq * 4;
    const int j0 = blockIdx.y * 256 + wc * 64 + l15;

#pragma unroll
    for (int mi = 0; mi < 8; ++mi) {
#pragma unroll
        for (int r = 0; r < 4; ++r) {
            const int i = i0 + mi * 16 + r;
            const float* qrow = QRb + (size_t)i * QR_STRIDE;
            const int* mrow = maskb + (size_t)i * Tn;
            float* orow = outb + (size_t)i * Tn;
#pragma unroll
            for (int ni = 0; ni < 4; ++ni) {
                const int j = j0 + ni * 16;
                int d = j - i;
                d = d < -Rn ? -Rn : (d > Rn ? Rn : d);
                const float qv = qrow[d + Rn];
                orow[j] = mrow[j] ? acc[mi][ni][r] + qv : -1e18f;
            }
        }
    }
}

extern "C" void kernel_launch(void* const* d_in, const int* in_sizes, int n_in,
                              void* d_out, int out_size, void* d_ws, size_t ws_size,
                              hipStream_t stream) {
    const float* repre  = (const float*)d_in[0];
    const int*   mask   = (const int*)  d_in[1];
    const float* st_Wq  = (const float*)d_in[2];
    const float* st_bq  = (const float*)d_in[3];
    const float* st_Wk  = (const float*)d_in[4];
    const float* st_bk  = (const float*)d_in[5];
    const float* st_rel = (const float*)d_in[6];
    const float* ed_Wq  = (const float*)d_in[7];
    const float* ed_bq  = (const float*)d_in[8];
    const float* ed_Wk  = (const float*)d_in[9];
    const float* ed_bk  = (const float*)d_in[10];
    const float* ed_rel = (const float*)d_in[11];
    float* out = (float*)d_out;

    const size_t MT = (size_t)Bn * Tn;   // 8192

    unsigned short* Xb   = (unsigned short*)d_ws;          // [8192][1024]
    unsigned short* Wb   = Xb + MT * Dn;                   // [4][1024][1024]
    unsigned short* relb = Wb + (size_t)4 * Dn * Dn;       // [2][256][1024]
    unsigned short* QKb  = relb + (size_t)2 * RELP * Dn;   // [4][8192][1024]
    float* QRbuf = (float*)(QKb + (size_t)4 * MT * Dn);    // [2][8192][132]

    const float qscale = 0.03125f;       // 1/sqrt(1024)
    dim3 blk(256);

    // Prep
    {
        int n4 = (int)(MT * Dn / 4);
        cvt_bf16<<<dim3((n4 + 255) / 256), blk, 0, stream>>>(repre, Xb, n4);
        wt_transpose<<<dim3(32, 32, 4), dim3(32, 8), 0, stream>>>(
            st_Wq, st_Wk, ed_Wq, ed_Wk, Wb);
        rel_pad<<<dim3(RELP * Dn / 4 / 256, 2), blk, 0, stream>>>(st_rel, ed_rel, relb);
    }

    // Projections (z: 0=st_q,1=st_k,2=ed_q,3=ed_k)
    proj_gemm256<<<dim3((int)MT / 256, Dn / 256, 4), dim3(512), 0, stream>>>(
        Xb, Wb, st_bq, st_bk, ed_bq, ed_bk, QKb, qscale);

    // qr (z=side), legacy path
    qr_gemm<<<dim3((int)MT / 128, RELP / 128, 2), blk, 0, stream>>>(QKb, relb, QRbuf);

    // scores (z = side*4 + batch)
    scores_gemm256<<<dim3(Tn / 256, Tn / 256, 8), dim3(512), 0, stream>>>(
        QKb, QRbuf, mask, out);
}